// Round 1
// baseline (9121.482 us; speedup 1.0000x reference)
//
#include <hip/hip_runtime.h>
#include <hip/hip_bf16.h>

#define B_   64
#define S_   1024
#define D_   512
#define H_   512
#define NWG  64
#define HCW  8      // h-columns per workgroup
#define NT   256

typedef __attribute__((ext_vector_type(8))) short short8;
typedef __attribute__((ext_vector_type(4))) float f32x4;

// Swizzled byte offset into the LDS W tile: [gc][k] bf16, row = 2048 B.
__device__ __forceinline__ int wl_byte(int gc, int k) {
  return ((gc << 11) + (k << 1)) ^ ((gc & 7) << 4);
}
__device__ __forceinline__ float sigm(float v) { return 1.0f / (1.0f + __expf(-v)); }
__device__ __forceinline__ float tanh_(float v) { return 1.0f - 2.0f / (__expf(2.0f * v) + 1.0f); }
__device__ __forceinline__ short f2bf(float f) {
  __hip_bfloat16 h = __float2bfloat16(f);
  short s;
  __builtin_memcpy(&s, &h, 2);
  return s;
}

union U128 { unsigned long long u[2]; short8 s; };

// Cache-bypassing 16B store: h broadcast rows. Fire-and-forget; drained
// by the explicit s_waitcnt vmcnt(0) before the flag publish.
__device__ __forceinline__ void store_b128_sys(void* p, short8 v) {
  asm volatile("global_store_dwordx4 %0, %1, off sc0 sc1" :: "v"(p), "v"(v) : "memory");
}

__global__ __launch_bounds__(NT, 1) void lstm_persist(
    const float* __restrict__ xg,
    const float* __restrict__ Wf, const float* __restrict__ bfv,
    const float* __restrict__ Wi, const float* __restrict__ biv,
    const float* __restrict__ Wc, const float* __restrict__ bcv,
    const float* __restrict__ Wo, const float* __restrict__ bov,
    float* __restrict__ out,
    short* __restrict__ hb,          // [2][64][512] bf16 h broadcast (double buffered)
    unsigned int* __restrict__ flags) // [4 cohorts][64 wgs] u32, packed
{
  __shared__ short Wl[32 * 1024];    // 64 KB: W slice, [gc][k] bf16, swizzled

  const int tid  = threadIdx.x;
  const int wg   = blockIdx.x;
  const int lane = tid & 63;
  const int wid  = tid >> 6;         // wave id = row cohort (16 batch rows)

  // ---- one-time: stage this WG's W slice (transposed to [gc][k], bf16) ----
  {
    const float* Wg4[4] = {Wf, Wi, Wc, Wo};
    const int gc  = tid >> 3;        // 0..31
    const int seg = tid & 7;         // k segment of 128
    const float* Wsrc = Wg4[gc >> 3];
    const int col = wg * HCW + (gc & 7);
    for (int kk = 0; kk < 128; ++kk) {
      const int k = seg * 128 + kk;
      *(short*)((char*)Wl + wl_byte(gc, k)) = f2bf(Wsrc[(size_t)k * H_ + col]);
    }
  }

  // Transposed-C lane mapping: C'[gatecol][row]; col(lane&15) = batch row,
  // rowC = (lane>>4)*4 + reg = gatecol. q<2 holds f/g cols, q>=2 holds i/o.
  const int q    = lane >> 4;        // 0..3
  const int rr   = lane & 15;        // batch row within wave tile
  const int c0   = (q & 1) << 2;     // col-quad base within WG's 8 cols
  const int colq = wg * HCW + c0;    // global col-quad base
  float bF4[4], bI4[4], bG4[4], bO4[4];
#pragma unroll
  for (int r = 0; r < 4; ++r) {
    bF4[r] = bfv[colq + r]; bI4[r] = biv[colq + r];
    bG4[r] = bcv[colq + r]; bO4[r] = bov[colq + r];
  }

  __syncthreads();                   // Wl ready (only barrier in the kernel)

  // A/B fragment addressing (identical for both operand roles):
  // index = lane&15, 8 consecutive k at k = ks*32 + (lane>>4)*8.
  const int rowb = (wid << 4) + rr;  // this lane's batch row
  const int kb8  = (lane >> 4) << 3;
  const float* xbase = xg + (size_t)rowb * S_ * D_;
  unsigned int* myflags = flags + (wid << 6);   // this cohort's 64 flags (256 B)

  float cst[4] = {0.f, 0.f, 0.f, 0.f};   // cell state: 4 consecutive cols of row rowb

  for (int t = 0; t < S_; ++t) {
    const short* hrd = hb + (t & 1) * (B_ * H_);
    short*       hwr = hb + ((t + 1) & 1) * (B_ * H_);

    f32x4 acc0 = {0.f, 0.f, 0.f, 0.f};   // gatecols [0,16):  f | i   (transposed C)
    f32x4 acc1 = {0.f, 0.f, 0.f, 0.f};   // gatecols [16,32): g | o

    const float* xr = xbase + (size_t)t * D_;

    // ---- x-part first (no cross-WG dependency): overlaps the wait ----
#pragma unroll 4
    for (int ks = 0; ks < 16; ++ks) {
      const int kx = ks * 32 + kb8;
      f32x4 f0 = *(const f32x4*)(xr + kx);
      f32x4 f1 = *(const f32x4*)(xr + kx + 4);
      short8 a;
#pragma unroll
      for (int j = 0; j < 4; ++j) { a[j] = f2bf(f0[j]); a[4 + j] = f2bf(f1[j]); }
      const int kw = 512 + kx;
      short8 b0 = *(const short8*)((const char*)Wl + wl_byte(lane & 15, kw));
      short8 b1 = *(const short8*)((const char*)Wl + wl_byte(16 + (lane & 15), kw));
      acc0 = __builtin_amdgcn_mfma_f32_16x16x32_bf16(b0, a, acc0, 0, 0, 0);
      acc1 = __builtin_amdgcn_mfma_f32_16x16x32_bf16(b1, a, acc1, 0, 0, 0);
    }

    // ---- per-wave wait: cohort flags packed in 4 cache lines ----
    if (t > 0) {
      const unsigned int tgt = (unsigned int)t;
      unsigned int v;
      do {
        v = __hip_atomic_load(&myflags[lane], __ATOMIC_RELAXED,
                              __HIP_MEMORY_SCOPE_SYSTEM);
      } while (!__all((int)(v >= tgt)));
      asm volatile("" ::: "memory");   // compiler-only ordering; HW in-order/wave
    }

    // ---- h-part: cache-bypassing reads of the h_t broadcast (own 16 rows) ----
    const short* hrow = hrd + rowb * H_;
#pragma unroll
    for (int ks = 0; ks < 16; ++ks) {
      const int k0 = ks * 32 + kb8;
      const unsigned long long* hp = (const unsigned long long*)(hrow + k0);
      U128 u;
      u.u[0] = __hip_atomic_load(hp, __ATOMIC_RELAXED, __HIP_MEMORY_SCOPE_SYSTEM);
      u.u[1] = __hip_atomic_load(hp + 1, __ATOMIC_RELAXED, __HIP_MEMORY_SCOPE_SYSTEM);
      short8 b0 = *(const short8*)((const char*)Wl + wl_byte(lane & 15, k0));
      short8 b1 = *(const short8*)((const char*)Wl + wl_byte(16 + (lane & 15), k0));
      acc0 = __builtin_amdgcn_mfma_f32_16x16x32_bf16(b0, u.s, acc0, 0, 0, 0);
      acc1 = __builtin_amdgcn_mfma_f32_16x16x32_bf16(b1, u.s, acc1, 0, 0, 0);
    }

    // ---- epilogue: exchange f<->i / g<->o halves across lane^32 ----
    f32x4 x0, x1;
#pragma unroll
    for (int j = 0; j < 4; ++j) {
      x0[j] = __shfl_xor(acc0[j], 32);
      x1[j] = __shfl_xor(acc1[j], 32);
    }
    const bool lo = (q < 2);
    float hv[4];
#pragma unroll
    for (int r = 0; r < 4; ++r) {
      const float sF = (lo ? acc0[r] : x0[r]) + bF4[r];
      const float sI = (lo ? x0[r] : acc0[r]) + bI4[r];
      const float sG = (lo ? acc1[r] : x1[r]) + bG4[r];
      const float sO = (lo ? x1[r] : acc1[r]) + bO4[r];
      const float fg = sigm(sF);
      const float ig = sigm(sI);
      const float gg = tanh_(sG);
      const float og = sigm(sO);
      const float cn = cst[r] * fg + gg * ig;
      cst[r] = cn;
      hv[r] = og * tanh_(cn);
    }

    // ---- out: one 16B store per lane (4 consecutive cols of row rowb) ----
    if (lo) {
      f32x4 hv4;
#pragma unroll
      for (int r = 0; r < 4; ++r) hv4[r] = hv[r];
      *(f32x4*)(out + (size_t)rowb * ((size_t)S_ * H_) + (size_t)t * H_ + colq) = hv4;
      if (t == S_ - 1) {
        f32x4 c4;
#pragma unroll
        for (int r = 0; r < 4; ++r) c4[r] = cst[r];
        *(f32x4*)(out + (size_t)B_ * S_ * H_ + (size_t)rowb * H_ + colq) = hv4;
        *(f32x4*)(out + (size_t)B_ * S_ * H_ + (size_t)B_ * H_
                      + (size_t)rowb * H_ + colq) = c4;
      }
    }

    // ---- h broadcast: pack 4 bf16 (8B), merge col-quads via lane^16,
    //      one aligned 16B system store per batch row (q==0 lanes) ----
    unsigned long long hp8;
    {
      unsigned int l32 = (unsigned int)(unsigned short)f2bf(hv[0])
                       | ((unsigned int)(unsigned short)f2bf(hv[1]) << 16);
      unsigned int h32 = (unsigned int)(unsigned short)f2bf(hv[2])
                       | ((unsigned int)(unsigned short)f2bf(hv[3]) << 16);
      hp8 = (unsigned long long)l32 | ((unsigned long long)h32 << 32);
    }
    unsigned long long other = __shfl_xor(hp8, 16);  // partner col-quad, same row
    if (q == 0) {
      U128 u;
      u.u[0] = hp8;     // cols 0..3
      u.u[1] = other;   // cols 4..7
      store_b128_sys(hwr + rowb * H_ + wg * HCW, u.s);
    }

    // ---- per-wave publish: drain own stores, then one packed flag store.
    //      No __syncthreads: rows are produced/consumed per cohort. ----
    if (t < S_ - 1) {
      asm volatile("s_waitcnt vmcnt(0)" ::: "memory");
      if (lane == 0) {
        __hip_atomic_store(&flags[(wid << 6) + wg], (unsigned int)(t + 1),
                           __ATOMIC_RELAXED, __HIP_MEMORY_SCOPE_SYSTEM);
      }
    }
  }
}

extern "C" void kernel_launch(void* const* d_in, const int* in_sizes, int n_in,
                              void* d_out, int out_size, void* d_ws, size_t ws_size,
                              hipStream_t stream) {
  (void)in_sizes; (void)n_in; (void)out_size; (void)ws_size;
  const float* x  = (const float*)d_in[0];
  const float* Wf = (const float*)d_in[1];
  const float* bf = (const float*)d_in[2];
  const float* Wi = (const float*)d_in[3];
  const float* bi = (const float*)d_in[4];
  const float* Wc = (const float*)d_in[5];
  const float* bc = (const float*)d_in[6];
  const float* Wo = (const float*)d_in[7];
  const float* bo = (const float*)d_in[8];
  float* out = (float*)d_out;

  unsigned int* flags = (unsigned int*)d_ws;          // 1 KB used (4 cohorts x 64)
  short* hb = (short*)((char*)d_ws + 4096);           // 128 KB double buffer

  // zero: flags + both h broadcast buffers (h0 = 0); captured in the graph,
  // so every replay starts from a clean state.
  hipMemsetAsync(d_ws, 0, 4096 + 2 * B_ * H_ * 2, stream);

  lstm_persist<<<dim3(NWG), dim3(NT), 0, stream>>>(
      x, Wf, bf, Wi, bi, Wc, bc, Wo, bo, out, hb, flags);
}